// Round 7
// baseline (136.520 us; speedup 1.0000x reference)
//
#include <hip/hip_runtime.h>
#include <hip/hip_bf16.h>
#include <math.h>
#include <string.h>

#define BB 4
#define SS 2048
#define FF 64
#define HID 256
#define DD 128
#define HH 8
#define DK 16
#define NROWS (BB*SS)          // 8192
#define MROWS 32               // rows per MLP block
#define QPB 64                 // q rows per attn block (2 q-tiles x 32)
#define NQB (SS/QPB)           // 32
#define KSPLIT 4
#define KRANGE (SS/KSPLIT)     // 512
#define XSTR 72                // x LDS stride (bf16): 144B rows, 16B aligned
#define HSTR 264               // h LDS stride (bf16): 528B rows, 16B aligned
#define VROWS 17               // V rows incl. ones-row (row 16) for l-via-MFMA

#define QSCALE 0.3606737602222409f   // log2(e) / sqrt(DK)

typedef __attribute__((ext_vector_type(8))) short short8;
typedef __attribute__((ext_vector_type(16))) float float16v;

static __device__ __forceinline__ unsigned pk_bf16(float a, float b) {   // round-to-nearest pack
    __hip_bfloat16 ha = __float2bfloat16(a), hb = __float2bfloat16(b);
    unsigned short lo, hi;
    memcpy(&lo, &ha, 2); memcpy(&hi, &hb, 2);
    return ((unsigned)hi << 16) | (unsigned)lo;
}
static __device__ __forceinline__ unsigned trunc_pk(float a, float b) {  // 1-instr truncation pack
    return __builtin_amdgcn_perm(__float_as_uint(b), __float_as_uint(a), 0x07060302u);
}

// ---------------- Stage 0: weight convert + transpose to bf16 ----------------
// grid (6,4), block 256. m<3: W1[64][256] -> W1T[256][64]; m>=3: W2[256][128] -> W2T[128][256].
__global__ __launch_bounds__(256) void convert_kernel(
    const float* __restrict__ qW1, const float* __restrict__ kW1, const float* __restrict__ vW1,
    const float* __restrict__ qW2, const float* __restrict__ kW2, const float* __restrict__ vW2,
    __hip_bfloat16* __restrict__ W1T, __hip_bfloat16* __restrict__ W2T)
{
    const int m = blockIdx.x;
    const int quarter = blockIdx.y;
    const int t = threadIdx.x;
    if (m < 3) {
        const float* src = (m == 0) ? qW1 : (m == 1) ? kW1 : vW1;
        __hip_bfloat16* dst = W1T + (size_t)m * (FF * HID);
        const int c = t;                       // 0..255
        for (int k0 = quarter * 16; k0 < quarter * 16 + 16; k0 += 8) {
            float v[8];
            #pragma unroll
            for (int j = 0; j < 8; ++j) v[j] = src[(size_t)(k0 + j) * HID + c];
            uint4 u = make_uint4(pk_bf16(v[0], v[1]), pk_bf16(v[2], v[3]),
                                 pk_bf16(v[4], v[5]), pk_bf16(v[6], v[7]));
            *(uint4*)&dst[(size_t)c * FF + k0] = u;
        }
    } else {
        const float* src = (m == 3) ? qW2 : (m == 4) ? kW2 : vW2;
        __hip_bfloat16* dst = W2T + (size_t)(m - 3) * (HID * DD);
        const int c = t & 127;
        const int half = t >> 7;
        const int kb = quarter * 64 + half * 32;
        for (int k0 = kb; k0 < kb + 32; k0 += 8) {
            float v[8];
            #pragma unroll
            for (int j = 0; j < 8; ++j) v[j] = src[(size_t)(k0 + j) * DD + c];
            uint4 u = make_uint4(pk_bf16(v[0], v[1]), pk_bf16(v[2], v[3]),
                                 pk_bf16(v[4], v[5]), pk_bf16(v[6], v[7]));
            *(uint4*)&dst[(size_t)c * HID + k0] = u;
        }
    }
}

// ---------------- Stage 1: q/k/v MLP via MFMA, transposed (H^T / Y^T) ----------------
// grid (NROWS/MROWS, 3), block 256 = 4 waves. which: 0=q,1=k,2=v.
// Layer1: H^T[c][row] = W1T-frag (A) x x-frag (B). C-layout: col=row(=lane), regs=c ->
//   adjacent regs are adjacent channels: pack pairs -> dword LDS writes.
// Layer2: Y^T[d][row] = W2T-frag x H-frag. Epilogue packs channel pairs -> dwordx2 stores.
__global__ __launch_bounds__(256) void mlp_kernel(
    const float* __restrict__ x,
    const float* __restrict__ qb1, const float* __restrict__ kb1, const float* __restrict__ vb1,
    const float* __restrict__ qb2, const float* __restrict__ kb2, const float* __restrict__ vb2,
    const __hip_bfloat16* __restrict__ W1T, const __hip_bfloat16* __restrict__ W2T,
    __hip_bfloat16* __restrict__ Qb, __hip_bfloat16* __restrict__ Kb,
    __hip_bfloat16* __restrict__ Vt)
{
    const int blk   = blockIdx.x;
    const int which = blockIdx.y;
    const int t     = threadIdx.x;
    const int w     = t >> 6;
    const int lane  = t & 63;
    const int n     = lane & 31;
    const int hg    = lane >> 5;
    const int row0  = blk * MROWS;
    const int b     = row0 >> 11;          // batch
    const int s0    = row0 & (SS - 1);

    const float* b1 = (which == 0) ? qb1 : (which == 1) ? kb1 : vb1;
    const float* b2 = (which == 0) ? qb2 : (which == 1) ? kb2 : vb2;
    const __hip_bfloat16* W1m = W1T + (size_t)which * (FF * HID);
    const __hip_bfloat16* W2m = W2T + (size_t)which * (HID * DD);

    __shared__ __hip_bfloat16 smem[MROWS * HSTR];   // 16.9 KB, reused x -> h

    // ---- stage x as bf16, [row][k] stride XSTR ----
    {
        const int r  = t >> 3;              // 0..31
        const int k0 = (t & 7) * 8;         // 0..56
        const float* xp = x + (size_t)(row0 + r) * FF + k0;
        float4 a0 = *(const float4*)xp;
        float4 a1 = *(const float4*)(xp + 4);
        uint4 u = make_uint4(pk_bf16(a0.x, a0.y), pk_bf16(a0.z, a0.w),
                             pk_bf16(a1.x, a1.y), pk_bf16(a1.z, a1.w));
        *(uint4*)&smem[r * XSTR + k0] = u;
    }
    __syncthreads();

    // ---- layer1: two 32-channel tiles per wave ----
    const int c0a = w * 64, c0b = w * 64 + 32;
    float16v acc0, acc1;
    {
        // per-reg bias: c = 8g + 4hg + (r&3)
        #pragma unroll
        for (int g = 0; g < 4; ++g) {
            const float4 ba = *(const float4*)&b1[c0a + 8 * g + 4 * hg];
            const float4 bb = *(const float4*)&b1[c0b + 8 * g + 4 * hg];
            acc0[4*g+0] = ba.x; acc0[4*g+1] = ba.y; acc0[4*g+2] = ba.z; acc0[4*g+3] = ba.w;
            acc1[4*g+0] = bb.x; acc1[4*g+1] = bb.y; acc1[4*g+2] = bb.z; acc1[4*g+3] = bb.w;
        }
    }
    #pragma unroll
    for (int s = 0; s < 4; ++s) {
        const short8 xf = *(const short8*)&smem[n * XSTR + 16 * s + 8 * hg];  // B: x[row=n][k]
        const short8 a0 = *(const short8*)&W1m[(size_t)(c0a + n) * FF + 16 * s + 8 * hg];
        const short8 a1 = *(const short8*)&W1m[(size_t)(c0b + n) * FF + 16 * s + 8 * hg];
        acc0 = __builtin_amdgcn_mfma_f32_32x32x16_bf16(a0, xf, acc0, 0, 0, 0);
        acc1 = __builtin_amdgcn_mfma_f32_32x32x16_bf16(a1, xf, acc1, 0, 0, 0);
    }
    // ---- ELU (fast: native exp) ----
    #pragma unroll
    for (int i = 0; i < 16; ++i) {
        const float v0 = acc0[i], v1 = acc1[i];
        acc0[i] = (v0 > 0.f) ? v0 : (__expf(v0) - 1.f);
        acc1[i] = (v1 > 0.f) ? v1 : (__expf(v1) - 1.f);
    }
    __syncthreads();   // all x reads complete before overwrite

    // ---- write H^T pairs: sH[row=n][c], 8 dword writes per tile ----
    #pragma unroll
    for (int g = 0; g < 4; ++g) {
        const int ca = c0a + 8 * g + 4 * hg;
        const int cb = c0b + 8 * g + 4 * hg;
        *(unsigned*)&smem[n * HSTR + ca]     = pk_bf16(acc0[4*g+0], acc0[4*g+1]);
        *(unsigned*)&smem[n * HSTR + ca + 2] = pk_bf16(acc0[4*g+2], acc0[4*g+3]);
        *(unsigned*)&smem[n * HSTR + cb]     = pk_bf16(acc1[4*g+0], acc1[4*g+1]);
        *(unsigned*)&smem[n * HSTR + cb + 2] = pk_bf16(acc1[4*g+2], acc1[4*g+3]);
    }
    __syncthreads();

    // ---- layer2: one 32-channel tile per wave, K=256 ----
    const int d0 = w * 32;
    float16v acc;
    #pragma unroll
    for (int g = 0; g < 4; ++g) {
        const float4 bv = *(const float4*)&b2[d0 + 8 * g + 4 * hg];
        acc[4*g+0] = bv.x; acc[4*g+1] = bv.y; acc[4*g+2] = bv.z; acc[4*g+3] = bv.w;
    }
    #pragma unroll 4
    for (int s = 0; s < 16; ++s) {
        const short8 hf = *(const short8*)&smem[n * HSTR + 16 * s + 8 * hg];
        const short8 af = *(const short8*)&W2m[(size_t)(d0 + n) * HID + 16 * s + 8 * hg];
        acc = __builtin_amdgcn_mfma_f32_32x32x16_bf16(af, hf, acc, 0, 0, 0);
    }

    // ---- epilogue: lane holds Y^T[d][row=n], d = d0 + 8g + 4hg + (r&3) ----
    if (which < 2) {
        const float sc = (which == 0) ? QSCALE : 1.0f;
        __hip_bfloat16* dst = (which == 0) ? Qb : Kb;
        #pragma unroll
        for (int g = 0; g < 4; ++g) {
            const int d  = d0 + 8 * g + 4 * hg;
            const int hh = d >> 4;
            const int dk = d & 15;
            const size_t base = ((size_t)(b * HH + hh) * SS + s0 + n) * DK + dk;
            uint2 u = make_uint2(pk_bf16(acc[4*g+0] * sc, acc[4*g+1] * sc),
                                 pk_bf16(acc[4*g+2] * sc, acc[4*g+3] * sc));
            *(uint2*)&dst[base] = u;
        }
    } else {
        #pragma unroll
        for (int r = 0; r < 16; ++r) {
            const int d  = d0 + 8 * (r >> 2) + 4 * hg + (r & 3);
            const int hh = d >> 4;
            const int dv = d & 15;
            Vt[((size_t)(b * HH + hh) * VROWS + dv) * SS + s0 + n] = __float2bfloat16(acc[r]);
        }
        // ones-row (d=16) for l-via-MFMA: 8 heads x 32 s
        const int hh2 = t >> 5, sl = t & 31;
        Vt[((size_t)(b * HH + hh2) * VROWS + 16) * SS + s0 + sl] = __float2bfloat16(1.0f);
    }
}

// ---------------- Stage 2: MFMA 32x32 flash attention, shuffle-free PV ----------------
// grid (NQB, HH, BB), block 512 = 8 waves: wave w -> q-tile (w>>2), key-split (w&3).
// Key-permutation trick: PV A-frag = the lane's own packed P regs (keys {0-3,8-11}+4hg etc.);
// the V B-frag loads the matching permuted s-offsets (2x dwordx2). No cross-lane ops.
// l computed by the PV MFMA via the ones-row (C col 16); truncation bias cancels in O/l.
__global__ __launch_bounds__(512, 8) void attn_kernel(
    const __hip_bfloat16* __restrict__ Qb,
    const __hip_bfloat16* __restrict__ Kb,
    const __hip_bfloat16* __restrict__ Vt,
    float* __restrict__ partial)
{
    const int qblk = blockIdx.x;
    const int h    = blockIdx.y;
    const int b    = blockIdx.z;
    const int bh   = b * HH + h;
    const int t    = threadIdx.x;
    const int w    = t >> 6;
    const int lane = t & 63;
    const int qt   = w >> 2;
    const int sp   = w & 3;
    const int n    = lane & 31;
    const int hg   = lane >> 5;

    __shared__ float sO[8][32][DK];
    __shared__ float sL[8][32];
    __shared__ float sV[QPB][DK];
    __shared__ float sM2[8][DK];

    const size_t bh_s = (size_t)bh * SS;
    const int q0 = qblk * QPB + qt * 32;

    const short8 qf = *(const short8*)(Qb + (bh_s + q0 + n) * DK + hg * 8);

    const __hip_bfloat16* kptr = Kb + (bh_s + sp * KRANGE) * DK + hg * 8;
    const int vd = (n < 16) ? n : 16;
    const __hip_bfloat16* vptr = Vt + ((size_t)bh * VROWS + vd) * SS + sp * KRANGE + 4 * hg;

    float16v acc;
    #pragma unroll
    for (int i = 0; i < 16; ++i) acc[i] = 0.f;
    float16v z;
    #pragma unroll
    for (int i = 0; i < 16; ++i) z[i] = 0.f;

    for (int kb = 0; kb < KRANGE; kb += 32) {
        const short8 kf = *(const short8*)(kptr + (size_t)(kb + n) * DK);

        union { uint2 u2[2]; short8 s8; } B1, B2;
        B1.u2[0] = *(const uint2*)(vptr + kb);        // keys {0..3}+4hg
        B1.u2[1] = *(const uint2*)(vptr + kb + 8);    // keys {8..11}+4hg
        B2.u2[0] = *(const uint2*)(vptr + kb + 16);   // keys {16..19}+4hg
        B2.u2[1] = *(const uint2*)(vptr + kb + 24);   // keys {24..27}+4hg

        // S^T[key][q]: col=n=q, key(reg,hg) = (reg&3)+8*(reg>>2)+4*hg
        const float16v st = __builtin_amdgcn_mfma_f32_32x32x16_bf16(kf, qf, z, 0, 0, 0);

        union { unsigned u[4]; short8 s8; } A1, A2;
        #pragma unroll
        for (int j = 0; j < 4; ++j)
            A1.u[j] = trunc_pk(exp2f(st[2 * j]),     exp2f(st[2 * j + 1]));
        #pragma unroll
        for (int j = 0; j < 4; ++j)
            A2.u[j] = trunc_pk(exp2f(st[2 * j + 8]), exp2f(st[2 * j + 9]));

        // O[q][d] (+ l in col 16): A-slots and B-slots share the permuted key order
        acc = __builtin_amdgcn_mfma_f32_32x32x16_bf16(A1.s8, B1.s8, acc, 0, 0, 0);
        acc = __builtin_amdgcn_mfma_f32_32x32x16_bf16(A2.s8, B2.s8, acc, 0, 0, 0);
    }

    // C-layout: col=n (0-15 -> O[q][d], 16 -> l[q]); q = (reg&3)+8*(reg>>2)+4*hg
    if (n < 16) {
        #pragma unroll
        for (int r = 0; r < 16; ++r) {
            const int q = (r & 3) + 8 * (r >> 2) + 4 * hg;
            sO[w][q][n] = acc[r];
        }
    } else if (n == 16) {
        #pragma unroll
        for (int r = 0; r < 16; ++r) {
            const int q = (r & 3) + 8 * (r >> 2) + 4 * hg;
            sL[w][q] = acc[r];
        }
    }
    __syncthreads();

    // merge 4 splits (pure sums) + normalize
    for (int it = t; it < QPB * DK; it += 512) {
        const int qt2 = it >> 9;
        const int q   = (it >> 4) & 31;
        const int d   = it & 15;
        const int w0  = qt2 * 4;
        const float Ov = sO[w0][q][d] + sO[w0+1][q][d] + sO[w0+2][q][d] + sO[w0+3][q][d];
        const float Lv = sL[w0][q] + sL[w0+1][q] + sL[w0+2][q] + sL[w0+3][q];
        sV[qt2 * 32 + q][d] = Ov / Lv;
    }
    __syncthreads();

    if (t < 128) {
        const int d = t & 15, g = t >> 4;
        float mx = sV[g * 8][d];
        #pragma unroll
        for (int i = 1; i < 8; ++i) mx = fmaxf(mx, sV[g * 8 + i][d]);
        sM2[g][d] = mx;
    }
    __syncthreads();

    if (t < DK) {
        float mx = sM2[0][t];
        #pragma unroll
        for (int g = 1; g < 8; ++g) mx = fmaxf(mx, sM2[g][t]);
        partial[((size_t)bh * NQB + qblk) * DK + t] = mx;
    }
}

// ---------------- Stage 3: reduce q-blocks -> output ----------------
__global__ void reduce_kernel(const float* __restrict__ partial,
                              float* __restrict__ out)
{
    const int g   = blockIdx.x * 256 + threadIdx.x;   // 0..511
    const int b   = g >> 7;
    const int col = g & 127;
    const int h   = col >> 4;
    const int d   = col & 15;
    float m = -1e30f;
    #pragma unroll
    for (int c = 0; c < NQB; ++c)
        m = fmaxf(m, partial[((size_t)(b * HH + h) * NQB + c) * DK + d]);
    out[g] = m;
}

extern "C" void kernel_launch(void* const* d_in, const int* in_sizes, int n_in,
                              void* d_out, int out_size, void* d_ws, size_t ws_size,
                              hipStream_t stream)
{
    const float* x   = (const float*)d_in[0];
    const float* qW1 = (const float*)d_in[1];
    const float* qb1 = (const float*)d_in[2];
    const float* qW2 = (const float*)d_in[3];
    const float* qb2 = (const float*)d_in[4];
    const float* kW1 = (const float*)d_in[5];
    const float* kb1 = (const float*)d_in[6];
    const float* kW2 = (const float*)d_in[7];
    const float* kb2 = (const float*)d_in[8];
    const float* vW1 = (const float*)d_in[9];
    const float* vb1 = (const float*)d_in[10];
    const float* vW2 = (const float*)d_in[11];
    const float* vb2 = (const float*)d_in[12];

    char* ws = (char*)d_ws;
    __hip_bfloat16* Qb  = (__hip_bfloat16*)(ws);                               // 2 MB
    __hip_bfloat16* Kb  = (__hip_bfloat16*)(ws + (size_t)2 * 1024 * 1024);     // 2 MB
    __hip_bfloat16* Vt  = (__hip_bfloat16*)(ws + (size_t)4 * 1024 * 1024);     // 2.23 MB (17 rows)
    __hip_bfloat16* W1T = (__hip_bfloat16*)(ws + (size_t)6400 * 1024);         // 96 KB
    __hip_bfloat16* W2T = (__hip_bfloat16*)(ws + (size_t)6528 * 1024);         // 192 KB
    float* partial      = (float*)(ws + (size_t)6784 * 1024);                  // 64 KB

    convert_kernel<<<dim3(6, 4), 256, 0, stream>>>(qW1, kW1, vW1, qW2, kW2, vW2, W1T, W2T);

    mlp_kernel<<<dim3(NROWS / MROWS, 3), 256, 0, stream>>>(
        x, qb1, kb1, vb1, qb2, kb2, vb2, W1T, W2T, Qb, Kb, Vt);

    attn_kernel<<<dim3(NQB, HH, BB), 512, 0, stream>>>(Qb, Kb, Vt, partial);

    reduce_kernel<<<2, 256, 0, stream>>>(partial, (float*)d_out);
}

// Round 8
// 120.280 us; speedup vs baseline: 1.1350x; 1.1350x over previous
//
#include <hip/hip_runtime.h>
#include <hip/hip_bf16.h>
#include <math.h>
#include <string.h>

#define BB 4
#define SS 2048
#define FF 64
#define HID 256
#define DD 128
#define HH 8
#define DK 16
#define NROWS (BB*SS)          // 8192
#define MROWS 32               // rows per MLP block
#define QPB 64                 // q rows per attn block (2 q-tiles x 32)
#define NQB (SS/QPB)           // 32
#define KSPLIT 4
#define KRANGE (SS/KSPLIT)     // 512
#define XSTR 72                // x LDS stride (bf16): 144B rows, 16B aligned
#define HSTR 264               // h LDS stride (bf16): 528B rows, 16B aligned
#define VROWS 17               // V rows incl. ones-row (row 16) for l-via-MFMA

#define QSCALE 0.3606737602222409f   // log2(e) / sqrt(DK)

typedef __attribute__((ext_vector_type(8))) short short8;
typedef __attribute__((ext_vector_type(16))) float float16v;

static __device__ __forceinline__ unsigned pk_bf16(float a, float b) {   // round-to-nearest pack
    __hip_bfloat16 ha = __float2bfloat16(a), hb = __float2bfloat16(b);
    unsigned short lo, hi;
    memcpy(&lo, &ha, 2); memcpy(&hi, &hb, 2);
    return ((unsigned)hi << 16) | (unsigned)lo;
}
static __device__ __forceinline__ unsigned trunc_pk(float a, float b) {  // 1-instr truncation pack
    return __builtin_amdgcn_perm(__float_as_uint(b), __float_as_uint(a), 0x07060302u);
}
static __device__ __forceinline__ float fexp2(float x) {                 // raw v_exp_f32
    return __builtin_amdgcn_exp2f(x);
}

// ---------------- Stage 0: weight convert + transpose to bf16 ----------------
// grid (6,4), block 256. m<3: W1[64][256] -> W1T[256][64]; m>=3: W2[256][128] -> W2T[128][256].
__global__ __launch_bounds__(256) void convert_kernel(
    const float* __restrict__ qW1, const float* __restrict__ kW1, const float* __restrict__ vW1,
    const float* __restrict__ qW2, const float* __restrict__ kW2, const float* __restrict__ vW2,
    __hip_bfloat16* __restrict__ W1T, __hip_bfloat16* __restrict__ W2T)
{
    const int m = blockIdx.x;
    const int quarter = blockIdx.y;
    const int t = threadIdx.x;
    if (m < 3) {
        const float* src = (m == 0) ? qW1 : (m == 1) ? kW1 : vW1;
        __hip_bfloat16* dst = W1T + (size_t)m * (FF * HID);
        const int c = t;                       // 0..255
        for (int k0 = quarter * 16; k0 < quarter * 16 + 16; k0 += 8) {
            float v[8];
            #pragma unroll
            for (int j = 0; j < 8; ++j) v[j] = src[(size_t)(k0 + j) * HID + c];
            uint4 u = make_uint4(pk_bf16(v[0], v[1]), pk_bf16(v[2], v[3]),
                                 pk_bf16(v[4], v[5]), pk_bf16(v[6], v[7]));
            *(uint4*)&dst[(size_t)c * FF + k0] = u;
        }
    } else {
        const float* src = (m == 3) ? qW2 : (m == 4) ? kW2 : vW2;
        __hip_bfloat16* dst = W2T + (size_t)(m - 3) * (HID * DD);
        const int c = t & 127;
        const int half = t >> 7;
        const int kb = quarter * 64 + half * 32;
        for (int k0 = kb; k0 < kb + 32; k0 += 8) {
            float v[8];
            #pragma unroll
            for (int j = 0; j < 8; ++j) v[j] = src[(size_t)(k0 + j) * DD + c];
            uint4 u = make_uint4(pk_bf16(v[0], v[1]), pk_bf16(v[2], v[3]),
                                 pk_bf16(v[4], v[5]), pk_bf16(v[6], v[7]));
            *(uint4*)&dst[(size_t)c * HID + k0] = u;
        }
    }
}

// ---------------- Stage 1: q/k/v MLP via MFMA, transposed (H^T / Y^T) ----------------
// grid (NROWS/MROWS, 3), block 256 = 4 waves. which: 0=q,1=k,2=v.
// V is stored with each 32-key group permuted into PV B-frag slot order so the
// attention kernel can load the B operand with a single b128 per MFMA.
__global__ __launch_bounds__(256) void mlp_kernel(
    const float* __restrict__ x,
    const float* __restrict__ qb1, const float* __restrict__ kb1, const float* __restrict__ vb1,
    const float* __restrict__ qb2, const float* __restrict__ kb2, const float* __restrict__ vb2,
    const __hip_bfloat16* __restrict__ W1T, const __hip_bfloat16* __restrict__ W2T,
    __hip_bfloat16* __restrict__ Qb, __hip_bfloat16* __restrict__ Kb,
    __hip_bfloat16* __restrict__ Vt)
{
    const int blk   = blockIdx.x;
    const int which = blockIdx.y;
    const int t     = threadIdx.x;
    const int w     = t >> 6;
    const int lane  = t & 63;
    const int n     = lane & 31;
    const int hg    = lane >> 5;
    const int row0  = blk * MROWS;
    const int b     = row0 >> 11;          // batch
    const int s0    = row0 & (SS - 1);

    const float* b1 = (which == 0) ? qb1 : (which == 1) ? kb1 : vb1;
    const float* b2 = (which == 0) ? qb2 : (which == 1) ? kb2 : vb2;
    const __hip_bfloat16* W1m = W1T + (size_t)which * (FF * HID);
    const __hip_bfloat16* W2m = W2T + (size_t)which * (HID * DD);

    __shared__ __hip_bfloat16 smem[MROWS * HSTR];   // 16.9 KB, reused x -> h

    // ---- stage x as bf16, [row][k] stride XSTR ----
    {
        const int r  = t >> 3;              // 0..31
        const int k0 = (t & 7) * 8;         // 0..56
        const float* xp = x + (size_t)(row0 + r) * FF + k0;
        float4 a0 = *(const float4*)xp;
        float4 a1 = *(const float4*)(xp + 4);
        uint4 u = make_uint4(pk_bf16(a0.x, a0.y), pk_bf16(a0.z, a0.w),
                             pk_bf16(a1.x, a1.y), pk_bf16(a1.z, a1.w));
        *(uint4*)&smem[r * XSTR + k0] = u;
    }
    __syncthreads();

    // ---- layer1: two 32-channel tiles per wave ----
    const int c0a = w * 64, c0b = w * 64 + 32;
    float16v acc0, acc1;
    {
        #pragma unroll
        for (int g = 0; g < 4; ++g) {
            const float4 ba = *(const float4*)&b1[c0a + 8 * g + 4 * hg];
            const float4 bb = *(const float4*)&b1[c0b + 8 * g + 4 * hg];
            acc0[4*g+0] = ba.x; acc0[4*g+1] = ba.y; acc0[4*g+2] = ba.z; acc0[4*g+3] = ba.w;
            acc1[4*g+0] = bb.x; acc1[4*g+1] = bb.y; acc1[4*g+2] = bb.z; acc1[4*g+3] = bb.w;
        }
    }
    #pragma unroll
    for (int s = 0; s < 4; ++s) {
        const short8 xf = *(const short8*)&smem[n * XSTR + 16 * s + 8 * hg];  // B: x[row=n][k]
        const short8 a0 = *(const short8*)&W1m[(size_t)(c0a + n) * FF + 16 * s + 8 * hg];
        const short8 a1 = *(const short8*)&W1m[(size_t)(c0b + n) * FF + 16 * s + 8 * hg];
        acc0 = __builtin_amdgcn_mfma_f32_32x32x16_bf16(a0, xf, acc0, 0, 0, 0);
        acc1 = __builtin_amdgcn_mfma_f32_32x32x16_bf16(a1, xf, acc1, 0, 0, 0);
    }
    // ---- ELU (native exp) ----
    #pragma unroll
    for (int i = 0; i < 16; ++i) {
        const float v0 = acc0[i], v1 = acc1[i];
        acc0[i] = (v0 > 0.f) ? v0 : (__expf(v0) - 1.f);
        acc1[i] = (v1 > 0.f) ? v1 : (__expf(v1) - 1.f);
    }
    __syncthreads();   // all x reads complete before overwrite

    // ---- write H^T pairs: sH[row=n][c], 8 dword writes per tile ----
    #pragma unroll
    for (int g = 0; g < 4; ++g) {
        const int ca = c0a + 8 * g + 4 * hg;
        const int cb = c0b + 8 * g + 4 * hg;
        *(unsigned*)&smem[n * HSTR + ca]     = pk_bf16(acc0[4*g+0], acc0[4*g+1]);
        *(unsigned*)&smem[n * HSTR + ca + 2] = pk_bf16(acc0[4*g+2], acc0[4*g+3]);
        *(unsigned*)&smem[n * HSTR + cb]     = pk_bf16(acc1[4*g+0], acc1[4*g+1]);
        *(unsigned*)&smem[n * HSTR + cb + 2] = pk_bf16(acc1[4*g+2], acc1[4*g+3]);
    }
    __syncthreads();

    // ---- layer2: one 32-channel tile per wave, K=256 ----
    const int d0 = w * 32;
    float16v acc;
    #pragma unroll
    for (int g = 0; g < 4; ++g) {
        const float4 bv = *(const float4*)&b2[d0 + 8 * g + 4 * hg];
        acc[4*g+0] = bv.x; acc[4*g+1] = bv.y; acc[4*g+2] = bv.z; acc[4*g+3] = bv.w;
    }
    #pragma unroll 4
    for (int s = 0; s < 16; ++s) {
        const short8 hf = *(const short8*)&smem[n * HSTR + 16 * s + 8 * hg];
        const short8 af = *(const short8*)&W2m[(size_t)(d0 + n) * HID + 16 * s + 8 * hg];
        acc = __builtin_amdgcn_mfma_f32_32x32x16_bf16(af, hf, acc, 0, 0, 0);
    }

    // ---- epilogue: lane holds Y^T[d][row=n], d = d0 + 8g + 4hg + (r&3) ----
    if (which < 2) {
        const float sc = (which == 0) ? QSCALE : 1.0f;
        __hip_bfloat16* dst = (which == 0) ? Qb : Kb;
        #pragma unroll
        for (int g = 0; g < 4; ++g) {
            const int d  = d0 + 8 * g + 4 * hg;
            const int hh = d >> 4;
            const int dk = d & 15;
            const size_t base = ((size_t)(b * HH + hh) * SS + s0 + n) * DK + dk;
            uint2 u = make_uint2(pk_bf16(acc[4*g+0] * sc, acc[4*g+1] * sc),
                                 pk_bf16(acc[4*g+2] * sc, acc[4*g+3] * sc));
            *(uint2*)&dst[base] = u;
        }
    } else {
        // permuted column: 32-key group laid out in PV B-frag slot order
        const int pos = (n & 16) | (((n >> 2) & 1) << 3) | (((n >> 3) & 1) << 2) | (n & 3);
        #pragma unroll
        for (int r = 0; r < 16; ++r) {
            const int d  = d0 + 8 * (r >> 2) + 4 * hg + (r & 3);
            const int hh = d >> 4;
            const int dv = d & 15;
            Vt[((size_t)(b * HH + hh) * VROWS + dv) * SS + s0 + pos] = __float2bfloat16(acc[r]);
        }
        // ones-row (d=16) for l-via-MFMA (order irrelevant: all ones)
        const int hh2 = t >> 5, sl = t & 31;
        Vt[((size_t)(b * HH + hh2) * VROWS + 16) * SS + s0 + sl] = __float2bfloat16(1.0f);
    }
}

// ---------------- Stage 2: MFMA 32x32 flash attention ----------------
// grid (NQB, HH, BB), block 512 = 8 waves: wave w -> q-tile (w>>2), key-split (w&3).
// Native v_exp_f32; P stays in-lane (key-permuted PV); V pre-permuted -> b128 B-frags.
// l computed by the PV MFMA via the ones-row (C col 16); truncation bias cancels in O/l.
__global__ __launch_bounds__(512, 8) void attn_kernel(
    const __hip_bfloat16* __restrict__ Qb,
    const __hip_bfloat16* __restrict__ Kb,
    const __hip_bfloat16* __restrict__ Vt,
    float* __restrict__ partial)
{
    const int qblk = blockIdx.x;
    const int h    = blockIdx.y;
    const int b    = blockIdx.z;
    const int bh   = b * HH + h;
    const int t    = threadIdx.x;
    const int w    = t >> 6;
    const int lane = t & 63;
    const int qt   = w >> 2;
    const int sp   = w & 3;
    const int n    = lane & 31;
    const int hg   = lane >> 5;

    __shared__ float sO[8][32][DK];
    __shared__ float sL[8][32];
    __shared__ float sV[QPB][DK];
    __shared__ float sM2[8][DK];

    const size_t bh_s = (size_t)bh * SS;
    const int q0 = qblk * QPB + qt * 32;

    const short8 qf = *(const short8*)(Qb + (bh_s + q0 + n) * DK + hg * 8);

    const __hip_bfloat16* kptr = Kb + (bh_s + sp * KRANGE) * DK + hg * 8;
    const int vd = (n < 16) ? n : 16;
    const __hip_bfloat16* vptr = Vt + ((size_t)bh * VROWS + vd) * SS + sp * KRANGE + 8 * hg;

    float16v acc;
    #pragma unroll
    for (int i = 0; i < 16; ++i) acc[i] = 0.f;
    float16v z;
    #pragma unroll
    for (int i = 0; i < 16; ++i) z[i] = 0.f;

    for (int kb = 0; kb < KRANGE; kb += 32) {
        const short8 kf = *(const short8*)(kptr + (size_t)(kb + n) * DK);
        const short8 B1 = *(const short8*)(vptr + kb);        // slots: keys {0-3,8-11}+4hg
        const short8 B2 = *(const short8*)(vptr + kb + 16);   // slots: keys {16-19,24-27}+4hg

        // S^T[key][q]: col=n=q, key(reg,hg) = (reg&3)+8*(reg>>2)+4*hg
        const float16v st = __builtin_amdgcn_mfma_f32_32x32x16_bf16(kf, qf, z, 0, 0, 0);

        union { unsigned u[4]; short8 s8; } A1, A2;
        #pragma unroll
        for (int j = 0; j < 4; ++j)
            A1.u[j] = trunc_pk(fexp2(st[2 * j]),     fexp2(st[2 * j + 1]));
        #pragma unroll
        for (int j = 0; j < 4; ++j)
            A2.u[j] = trunc_pk(fexp2(st[2 * j + 8]), fexp2(st[2 * j + 9]));

        // O[q][d] (+ l in col 16): A-slots and B-slots share the permuted key order
        acc = __builtin_amdgcn_mfma_f32_32x32x16_bf16(A1.s8, B1, acc, 0, 0, 0);
        acc = __builtin_amdgcn_mfma_f32_32x32x16_bf16(A2.s8, B2, acc, 0, 0, 0);
    }

    // C-layout: col=n (0-15 -> O[q][d], 16 -> l[q]); q = (reg&3)+8*(reg>>2)+4*hg
    if (n < 16) {
        #pragma unroll
        for (int r = 0; r < 16; ++r) {
            const int q = (r & 3) + 8 * (r >> 2) + 4 * hg;
            sO[w][q][n] = acc[r];
        }
    } else if (n == 16) {
        #pragma unroll
        for (int r = 0; r < 16; ++r) {
            const int q = (r & 3) + 8 * (r >> 2) + 4 * hg;
            sL[w][q] = acc[r];
        }
    }
    __syncthreads();

    // merge 4 splits (pure sums) + normalize
    for (int it = t; it < QPB * DK; it += 512) {
        const int qt2 = it >> 9;
        const int q   = (it >> 4) & 31;
        const int d   = it & 15;
        const int w0  = qt2 * 4;
        const float Ov = sO[w0][q][d] + sO[w0+1][q][d] + sO[w0+2][q][d] + sO[w0+3][q][d];
        const float Lv = sL[w0][q] + sL[w0+1][q] + sL[w0+2][q] + sL[w0+3][q];
        sV[qt2 * 32 + q][d] = Ov / Lv;
    }
    __syncthreads();

    if (t < 128) {
        const int d = t & 15, g = t >> 4;
        float mx = sV[g * 8][d];
        #pragma unroll
        for (int i = 1; i < 8; ++i) mx = fmaxf(mx, sV[g * 8 + i][d]);
        sM2[g][d] = mx;
    }
    __syncthreads();

    if (t < DK) {
        float mx = sM2[0][t];
        #pragma unroll
        for (int g = 1; g < 8; ++g) mx = fmaxf(mx, sM2[g][t]);
        partial[((size_t)bh * NQB + qblk) * DK + t] = mx;
    }
}

// ---------------- Stage 3: reduce q-blocks -> output ----------------
__global__ void reduce_kernel(const float* __restrict__ partial,
                              float* __restrict__ out)
{
    const int g   = blockIdx.x * 256 + threadIdx.x;   // 0..511
    const int b   = g >> 7;
    const int col = g & 127;
    const int h   = col >> 4;
    const int d   = col & 15;
    float m = -1e30f;
    #pragma unroll
    for (int c = 0; c < NQB; ++c)
        m = fmaxf(m, partial[((size_t)(b * HH + h) * NQB + c) * DK + d]);
    out[g] = m;
}

extern "C" void kernel_launch(void* const* d_in, const int* in_sizes, int n_in,
                              void* d_out, int out_size, void* d_ws, size_t ws_size,
                              hipStream_t stream)
{
    const float* x   = (const float*)d_in[0];
    const float* qW1 = (const float*)d_in[1];
    const float* qb1 = (const float*)d_in[2];
    const float* qW2 = (const float*)d_in[3];
    const float* qb2 = (const float*)d_in[4];
    const float* kW1 = (const float*)d_in[5];
    const float* kb1 = (const float*)d_in[6];
    const float* kW2 = (const float*)d_in[7];
    const float* kb2 = (const float*)d_in[8];
    const float* vW1 = (const float*)d_in[9];
    const float* vb1 = (const float*)d_in[10];
    const float* vW2 = (const float*)d_in[11];
    const float* vb2 = (const float*)d_in[12];

    char* ws = (char*)d_ws;
    __hip_bfloat16* Qb  = (__hip_bfloat16*)(ws);                               // 2 MB
    __hip_bfloat16* Kb  = (__hip_bfloat16*)(ws + (size_t)2 * 1024 * 1024);     // 2 MB
    __hip_bfloat16* Vt  = (__hip_bfloat16*)(ws + (size_t)4 * 1024 * 1024);     // 2.23 MB (17 rows)
    __hip_bfloat16* W1T = (__hip_bfloat16*)(ws + (size_t)6400 * 1024);         // 96 KB
    __hip_bfloat16* W2T = (__hip_bfloat16*)(ws + (size_t)6528 * 1024);         // 192 KB
    float* partial      = (float*)(ws + (size_t)6784 * 1024);                  // 64 KB

    convert_kernel<<<dim3(6, 4), 256, 0, stream>>>(qW1, kW1, vW1, qW2, kW2, vW2, W1T, W2T);

    mlp_kernel<<<dim3(NROWS / MROWS, 3), 256, 0, stream>>>(
        x, qb1, kb1, vb1, qb2, kb2, vb2, W1T, W2T, Qb, Kb, Vt);

    attn_kernel<<<dim3(NQB, HH, BB), 512, 0, stream>>>(Qb, Kb, Vt, partial);

    reduce_kernel<<<2, 256, 0, stream>>>(partial, (float*)d_out);
}

// Round 9
// 118.861 us; speedup vs baseline: 1.1486x; 1.0119x over previous
//
#include <hip/hip_runtime.h>
#include <hip/hip_bf16.h>
#include <math.h>
#include <string.h>

#define BB 4
#define SS 2048
#define FF 64
#define HID 256
#define DD 128
#define HH 8
#define DK 16
#define NROWS (BB*SS)          // 8192
#define MROWS 32               // rows per MLP block
#define QPB 64                 // q rows per attn block (2 q-tiles x 32)
#define NQB (SS/QPB)           // 32
#define KSPLIT 4
#define KRANGE (SS/KSPLIT)     // 512
#define XSTR 72                // x LDS stride (bf16): 144B rows, 16B aligned
#define HSTR 264               // h LDS stride (bf16): 528B rows, 16B aligned
#define VROWS 17               // V rows incl. ones-row (row 16) for l-via-MFMA

#define QSCALE 0.3606737602222409f   // log2(e) / sqrt(DK)

typedef __attribute__((ext_vector_type(8))) short short8;
typedef __attribute__((ext_vector_type(16))) float float16v;

static __device__ __forceinline__ unsigned pk_bf16(float a, float b) {   // round-to-nearest pack
    __hip_bfloat16 ha = __float2bfloat16(a), hb = __float2bfloat16(b);
    unsigned short lo, hi;
    memcpy(&lo, &ha, 2); memcpy(&hi, &hb, 2);
    return ((unsigned)hi << 16) | (unsigned)lo;
}
static __device__ __forceinline__ unsigned trunc_pk(float a, float b) {  // 1-instr truncation pack
    return __builtin_amdgcn_perm(__float_as_uint(b), __float_as_uint(a), 0x07060302u);
}
static __device__ __forceinline__ float fexp2(float x) {                 // raw v_exp_f32
    return __builtin_amdgcn_exp2f(x);
}

// ---------------- Stage 0: weight convert + transpose to bf16 ----------------
// grid (6,4), block 256. m<3: W1[64][256] -> W1T[256][64]; m>=3: W2[256][128] -> W2T[128][256].
__global__ __launch_bounds__(256) void convert_kernel(
    const float* __restrict__ qW1, const float* __restrict__ kW1, const float* __restrict__ vW1,
    const float* __restrict__ qW2, const float* __restrict__ kW2, const float* __restrict__ vW2,
    __hip_bfloat16* __restrict__ W1T, __hip_bfloat16* __restrict__ W2T)
{
    const int m = blockIdx.x;
    const int quarter = blockIdx.y;
    const int t = threadIdx.x;
    if (m < 3) {
        const float* src = (m == 0) ? qW1 : (m == 1) ? kW1 : vW1;
        __hip_bfloat16* dst = W1T + (size_t)m * (FF * HID);
        const int c = t;                       // 0..255
        for (int k0 = quarter * 16; k0 < quarter * 16 + 16; k0 += 8) {
            float v[8];
            #pragma unroll
            for (int j = 0; j < 8; ++j) v[j] = src[(size_t)(k0 + j) * HID + c];
            uint4 u = make_uint4(pk_bf16(v[0], v[1]), pk_bf16(v[2], v[3]),
                                 pk_bf16(v[4], v[5]), pk_bf16(v[6], v[7]));
            *(uint4*)&dst[(size_t)c * FF + k0] = u;
        }
    } else {
        const float* src = (m == 3) ? qW2 : (m == 4) ? kW2 : vW2;
        __hip_bfloat16* dst = W2T + (size_t)(m - 3) * (HID * DD);
        const int c = t & 127;
        const int half = t >> 7;
        const int kb = quarter * 64 + half * 32;
        for (int k0 = kb; k0 < kb + 32; k0 += 8) {
            float v[8];
            #pragma unroll
            for (int j = 0; j < 8; ++j) v[j] = src[(size_t)(k0 + j) * DD + c];
            uint4 u = make_uint4(pk_bf16(v[0], v[1]), pk_bf16(v[2], v[3]),
                                 pk_bf16(v[4], v[5]), pk_bf16(v[6], v[7]));
            *(uint4*)&dst[(size_t)c * HID + k0] = u;
        }
    }
}

// ---------------- Stage 1: q/k/v MLP via MFMA, transposed (H^T / Y^T) ----------------
// grid (NROWS/MROWS, 3), block 256 = 4 waves. which: 0=q,1=k,2=v.
// V stored with each 32-key group permuted into PV B-frag slot order.
__global__ __launch_bounds__(256) void mlp_kernel(
    const float* __restrict__ x,
    const float* __restrict__ qb1, const float* __restrict__ kb1, const float* __restrict__ vb1,
    const float* __restrict__ qb2, const float* __restrict__ kb2, const float* __restrict__ vb2,
    const __hip_bfloat16* __restrict__ W1T, const __hip_bfloat16* __restrict__ W2T,
    __hip_bfloat16* __restrict__ Qb, __hip_bfloat16* __restrict__ Kb,
    __hip_bfloat16* __restrict__ Vt)
{
    const int blk   = blockIdx.x;
    const int which = blockIdx.y;
    const int t     = threadIdx.x;
    const int w     = t >> 6;
    const int lane  = t & 63;
    const int n     = lane & 31;
    const int hg    = lane >> 5;
    const int row0  = blk * MROWS;
    const int b     = row0 >> 11;          // batch
    const int s0    = row0 & (SS - 1);

    const float* b1 = (which == 0) ? qb1 : (which == 1) ? kb1 : vb1;
    const float* b2 = (which == 0) ? qb2 : (which == 1) ? kb2 : vb2;
    const __hip_bfloat16* W1m = W1T + (size_t)which * (FF * HID);
    const __hip_bfloat16* W2m = W2T + (size_t)which * (HID * DD);

    __shared__ __hip_bfloat16 smem[MROWS * HSTR];   // 16.9 KB, reused x -> h

    // ---- stage x as bf16, [row][k] stride XSTR ----
    {
        const int r  = t >> 3;              // 0..31
        const int k0 = (t & 7) * 8;         // 0..56
        const float* xp = x + (size_t)(row0 + r) * FF + k0;
        float4 a0 = *(const float4*)xp;
        float4 a1 = *(const float4*)(xp + 4);
        uint4 u = make_uint4(pk_bf16(a0.x, a0.y), pk_bf16(a0.z, a0.w),
                             pk_bf16(a1.x, a1.y), pk_bf16(a1.z, a1.w));
        *(uint4*)&smem[r * XSTR + k0] = u;
    }
    __syncthreads();

    // ---- layer1: two 32-channel tiles per wave ----
    const int c0a = w * 64, c0b = w * 64 + 32;
    float16v acc0, acc1;
    {
        #pragma unroll
        for (int g = 0; g < 4; ++g) {
            const float4 ba = *(const float4*)&b1[c0a + 8 * g + 4 * hg];
            const float4 bb = *(const float4*)&b1[c0b + 8 * g + 4 * hg];
            acc0[4*g+0] = ba.x; acc0[4*g+1] = ba.y; acc0[4*g+2] = ba.z; acc0[4*g+3] = ba.w;
            acc1[4*g+0] = bb.x; acc1[4*g+1] = bb.y; acc1[4*g+2] = bb.z; acc1[4*g+3] = bb.w;
        }
    }
    #pragma unroll
    for (int s = 0; s < 4; ++s) {
        const short8 xf = *(const short8*)&smem[n * XSTR + 16 * s + 8 * hg];  // B: x[row=n][k]
        const short8 a0 = *(const short8*)&W1m[(size_t)(c0a + n) * FF + 16 * s + 8 * hg];
        const short8 a1 = *(const short8*)&W1m[(size_t)(c0b + n) * FF + 16 * s + 8 * hg];
        acc0 = __builtin_amdgcn_mfma_f32_32x32x16_bf16(a0, xf, acc0, 0, 0, 0);
        acc1 = __builtin_amdgcn_mfma_f32_32x32x16_bf16(a1, xf, acc1, 0, 0, 0);
    }
    // ---- ELU (native exp) ----
    #pragma unroll
    for (int i = 0; i < 16; ++i) {
        const float v0 = acc0[i], v1 = acc1[i];
        acc0[i] = (v0 > 0.f) ? v0 : (__expf(v0) - 1.f);
        acc1[i] = (v1 > 0.f) ? v1 : (__expf(v1) - 1.f);
    }
    __syncthreads();   // all x reads complete before overwrite

    // ---- write H^T pairs: sH[row=n][c], 8 dword writes per tile ----
    #pragma unroll
    for (int g = 0; g < 4; ++g) {
        const int ca = c0a + 8 * g + 4 * hg;
        const int cb = c0b + 8 * g + 4 * hg;
        *(unsigned*)&smem[n * HSTR + ca]     = pk_bf16(acc0[4*g+0], acc0[4*g+1]);
        *(unsigned*)&smem[n * HSTR + ca + 2] = pk_bf16(acc0[4*g+2], acc0[4*g+3]);
        *(unsigned*)&smem[n * HSTR + cb]     = pk_bf16(acc1[4*g+0], acc1[4*g+1]);
        *(unsigned*)&smem[n * HSTR + cb + 2] = pk_bf16(acc1[4*g+2], acc1[4*g+3]);
    }
    __syncthreads();

    // ---- layer2: one 32-channel tile per wave, K=256 ----
    const int d0 = w * 32;
    float16v acc;
    #pragma unroll
    for (int g = 0; g < 4; ++g) {
        const float4 bv = *(const float4*)&b2[d0 + 8 * g + 4 * hg];
        acc[4*g+0] = bv.x; acc[4*g+1] = bv.y; acc[4*g+2] = bv.z; acc[4*g+3] = bv.w;
    }
    #pragma unroll 8
    for (int s = 0; s < 16; ++s) {
        const short8 hf = *(const short8*)&smem[n * HSTR + 16 * s + 8 * hg];
        const short8 af = *(const short8*)&W2m[(size_t)(d0 + n) * HID + 16 * s + 8 * hg];
        acc = __builtin_amdgcn_mfma_f32_32x32x16_bf16(af, hf, acc, 0, 0, 0);
    }

    // ---- epilogue: lane holds Y^T[d][row=n], d = d0 + 8g + 4hg + (r&3) ----
    if (which < 2) {
        const float sc = (which == 0) ? QSCALE : 1.0f;
        __hip_bfloat16* dst = (which == 0) ? Qb : Kb;
        #pragma unroll
        for (int g = 0; g < 4; ++g) {
            const int d  = d0 + 8 * g + 4 * hg;
            const int hh = d >> 4;
            const int dk = d & 15;
            const size_t base = ((size_t)(b * HH + hh) * SS + s0 + n) * DK + dk;
            uint2 u = make_uint2(pk_bf16(acc[4*g+0] * sc, acc[4*g+1] * sc),
                                 pk_bf16(acc[4*g+2] * sc, acc[4*g+3] * sc));
            *(uint2*)&dst[base] = u;
        }
    } else {
        // permuted column: 32-key group laid out in PV B-frag slot order
        const int pos = (n & 16) | (((n >> 2) & 1) << 3) | (((n >> 3) & 1) << 2) | (n & 3);
        #pragma unroll
        for (int r = 0; r < 16; ++r) {
            const int d  = d0 + 8 * (r >> 2) + 4 * hg + (r & 3);
            const int hh = d >> 4;
            const int dv = d & 15;
            Vt[((size_t)(b * HH + hh) * VROWS + dv) * SS + s0 + pos] = __float2bfloat16(acc[r]);
        }
        // ones-row (d=16) for l-via-MFMA (order irrelevant: all ones)
        const int hh2 = t >> 5, sl = t & 31;
        Vt[((size_t)(b * HH + hh2) * VROWS + 16) * SS + s0 + sl] = __float2bfloat16(1.0f);
    }
}

// ---------------- Stage 2: MFMA 32x32 flash attention, software-pipelined ----------------
// grid (NQB, HH, BB), block 512 = 8 waves: wave w -> q-tile (w>>2), key-split (w&3).
// Next-tile kf/B1/B2 prefetched before the exp chain of the current tile (rotation);
// tail prefetch over-reads into mapped ws (harmless, unused). Native v_exp_f32;
// l via ones-row (C col 16); truncation bias cancels in O/l.
__global__ __launch_bounds__(512, 8) void attn_kernel(
    const __hip_bfloat16* __restrict__ Qb,
    const __hip_bfloat16* __restrict__ Kb,
    const __hip_bfloat16* __restrict__ Vt,
    float* __restrict__ partial)
{
    const int qblk = blockIdx.x;
    const int h    = blockIdx.y;
    const int b    = blockIdx.z;
    const int bh   = b * HH + h;
    const int t    = threadIdx.x;
    const int w    = t >> 6;
    const int lane = t & 63;
    const int qt   = w >> 2;
    const int sp   = w & 3;
    const int n    = lane & 31;
    const int hg   = lane >> 5;

    __shared__ float sO[8][32][DK];
    __shared__ float sL[8][32];
    __shared__ float sV[QPB][DK];
    __shared__ float sM2[8][DK];

    const size_t bh_s = (size_t)bh * SS;
    const int q0 = qblk * QPB + qt * 32;

    const short8 qf = *(const short8*)(Qb + (bh_s + q0 + n) * DK + hg * 8);

    // lane-fixed pointers
    const __hip_bfloat16* klp = Kb + (bh_s + sp * KRANGE + n) * DK + hg * 8;
    const int vd = (n < 16) ? n : 16;
    const __hip_bfloat16* vlp = Vt + ((size_t)bh * VROWS + vd) * SS + sp * KRANGE + 8 * hg;

    float16v acc;
    #pragma unroll
    for (int i = 0; i < 16; ++i) acc[i] = 0.f;
    float16v z;
    #pragma unroll
    for (int i = 0; i < 16; ++i) z[i] = 0.f;

    // prologue loads
    short8 kf = *(const short8*)klp;
    short8 B1 = *(const short8*)vlp;
    short8 B2 = *(const short8*)(vlp + 16);

    #pragma unroll 4
    for (int it = 0; it < KRANGE / 32; ++it) {
        // ---- prefetch next tile (over-reads on last iter land in mapped ws) ----
        klp += 32 * DK;
        vlp += 32;
        const short8 kf_n = *(const short8*)klp;
        const short8 B1_n = *(const short8*)vlp;
        const short8 B2_n = *(const short8*)(vlp + 16);

        // S^T[key][q]: col=n=q, key(reg,hg) = (reg&3)+8*(reg>>2)+4*hg
        const float16v st = __builtin_amdgcn_mfma_f32_32x32x16_bf16(kf, qf, z, 0, 0, 0);

        union { unsigned u[4]; short8 s8; } A1, A2;
        #pragma unroll
        for (int j = 0; j < 4; ++j)
            A1.u[j] = trunc_pk(fexp2(st[2 * j]),     fexp2(st[2 * j + 1]));
        #pragma unroll
        for (int j = 0; j < 4; ++j)
            A2.u[j] = trunc_pk(fexp2(st[2 * j + 8]), fexp2(st[2 * j + 9]));

        // O[q][d] (+ l in col 16): A-slots and B-slots share the permuted key order
        acc = __builtin_amdgcn_mfma_f32_32x32x16_bf16(A1.s8, B1, acc, 0, 0, 0);
        acc = __builtin_amdgcn_mfma_f32_32x32x16_bf16(A2.s8, B2, acc, 0, 0, 0);

        kf = kf_n; B1 = B1_n; B2 = B2_n;
    }

    // C-layout: col=n (0-15 -> O[q][d], 16 -> l[q]); q = (reg&3)+8*(reg>>2)+4*hg
    if (n < 16) {
        #pragma unroll
        for (int r = 0; r < 16; ++r) {
            const int q = (r & 3) + 8 * (r >> 2) + 4 * hg;
            sO[w][q][n] = acc[r];
        }
    } else if (n == 16) {
        #pragma unroll
        for (int r = 0; r < 16; ++r) {
            const int q = (r & 3) + 8 * (r >> 2) + 4 * hg;
            sL[w][q] = acc[r];
        }
    }
    __syncthreads();

    // merge 4 splits (pure sums) + normalize
    for (int it = t; it < QPB * DK; it += 512) {
        const int qt2 = it >> 9;
        const int q   = (it >> 4) & 31;
        const int d   = it & 15;
        const int w0  = qt2 * 4;
        const float Ov = sO[w0][q][d] + sO[w0+1][q][d] + sO[w0+2][q][d] + sO[w0+3][q][d];
        const float Lv = sL[w0][q] + sL[w0+1][q] + sL[w0+2][q] + sL[w0+3][q];
        sV[qt2 * 32 + q][d] = Ov / Lv;
    }
    __syncthreads();

    if (t < 128) {
        const int d = t & 15, g = t >> 4;
        float mx = sV[g * 8][d];
        #pragma unroll
        for (int i = 1; i < 8; ++i) mx = fmaxf(mx, sV[g * 8 + i][d]);
        sM2[g][d] = mx;
    }
    __syncthreads();

    if (t < DK) {
        float mx = sM2[0][t];
        #pragma unroll
        for (int g = 1; g < 8; ++g) mx = fmaxf(mx, sM2[g][t]);
        partial[((size_t)bh * NQB + qblk) * DK + t] = mx;
    }
}

// ---------------- Stage 3: reduce q-blocks -> output ----------------
__global__ void reduce_kernel(const float* __restrict__ partial,
                              float* __restrict__ out)
{
    const int g   = blockIdx.x * 256 + threadIdx.x;   // 0..511
    const int b   = g >> 7;
    const int col = g & 127;
    const int h   = col >> 4;
    const int d   = col & 15;
    float m = -1e30f;
    #pragma unroll
    for (int c = 0; c < NQB; ++c)
        m = fmaxf(m, partial[((size_t)(b * HH + h) * NQB + c) * DK + d]);
    out[g] = m;
}

extern "C" void kernel_launch(void* const* d_in, const int* in_sizes, int n_in,
                              void* d_out, int out_size, void* d_ws, size_t ws_size,
                              hipStream_t stream)
{
    const float* x   = (const float*)d_in[0];
    const float* qW1 = (const float*)d_in[1];
    const float* qb1 = (const float*)d_in[2];
    const float* qW2 = (const float*)d_in[3];
    const float* qb2 = (const float*)d_in[4];
    const float* kW1 = (const float*)d_in[5];
    const float* kb1 = (const float*)d_in[6];
    const float* kW2 = (const float*)d_in[7];
    const float* kb2 = (const float*)d_in[8];
    const float* vW1 = (const float*)d_in[9];
    const float* vb1 = (const float*)d_in[10];
    const float* vW2 = (const float*)d_in[11];
    const float* vb2 = (const float*)d_in[12];

    char* ws = (char*)d_ws;
    __hip_bfloat16* Qb  = (__hip_bfloat16*)(ws);                               // 2 MB
    __hip_bfloat16* Kb  = (__hip_bfloat16*)(ws + (size_t)2 * 1024 * 1024);     // 2 MB
    __hip_bfloat16* Vt  = (__hip_bfloat16*)(ws + (size_t)4 * 1024 * 1024);     // 2.23 MB (17 rows)
    __hip_bfloat16* W1T = (__hip_bfloat16*)(ws + (size_t)6400 * 1024);         // 96 KB
    __hip_bfloat16* W2T = (__hip_bfloat16*)(ws + (size_t)6528 * 1024);         // 192 KB
    float* partial      = (float*)(ws + (size_t)6784 * 1024);                  // 64 KB

    convert_kernel<<<dim3(6, 4), 256, 0, stream>>>(qW1, kW1, vW1, qW2, kW2, vW2, W1T, W2T);

    mlp_kernel<<<dim3(NROWS / MROWS, 3), 256, 0, stream>>>(
        x, qb1, kb1, vb1, qb2, kb2, vb2, W1T, W2T, Qb, Kb, Vt);

    attn_kernel<<<dim3(NQB, HH, BB), 512, 0, stream>>>(Qb, Kb, Vt, partial);

    reduce_kernel<<<2, 256, 0, stream>>>(partial, (float*)d_out);
}

// Round 10
// 116.412 us; speedup vs baseline: 1.1727x; 1.0210x over previous
//
#include <hip/hip_runtime.h>
#include <hip/hip_bf16.h>
#include <math.h>
#include <string.h>

#define BB 4
#define SS 2048
#define FF 64
#define HID 256
#define DD 128
#define HH 8
#define DK 16
#define NROWS (BB*SS)          // 8192
#define MROWS 32               // rows per MLP block
#define QPB 64                 // q rows per attn block (2 q-tiles x 32)
#define NQB (SS/QPB)           // 32
#define KSPLIT 4
#define KRANGE (SS/KSPLIT)     // 512
#define XSTR 72                // x LDS stride (bf16): 144B rows, 16B aligned
#define HSTR 264               // h LDS stride (bf16): 528B rows, 16B aligned
#define VROWS 17               // V rows incl. ones-row (row 16) for l-via-MFMA

#define QSCALE 0.3606737602222409f   // log2(e) / sqrt(DK)

typedef __attribute__((ext_vector_type(8))) short short8;
typedef __attribute__((ext_vector_type(16))) float float16v;

static __device__ __forceinline__ unsigned pk_bf16(float a, float b) {   // round-to-nearest pack
    __hip_bfloat16 ha = __float2bfloat16(a), hb = __float2bfloat16(b);
    unsigned short lo, hi;
    memcpy(&lo, &ha, 2); memcpy(&hi, &hb, 2);
    return ((unsigned)hi << 16) | (unsigned)lo;
}
static __device__ __forceinline__ unsigned trunc_pk(float a, float b) {  // 1-instr truncation pack
    return __builtin_amdgcn_perm(__float_as_uint(b), __float_as_uint(a), 0x07060302u);
}
static __device__ __forceinline__ float fexp2(float x) {                 // raw v_exp_f32
    return __builtin_amdgcn_exp2f(x);
}

// Load an 8-deep K-slice of a fp32 weight matrix column-block as a bf16 A-fragment.
// Lane needs W[k0+j][c] for j=0..7 (row stride = ncols); each of the 8 loads is
// lane-coalesced (consecutive c across lanes). RN pack matches the old convert kernel.
static __device__ __forceinline__ short8 wfrag_f32(const float* __restrict__ W,
                                                   int k0, int c, int ncols) {
    const float* p = W + (size_t)k0 * ncols + c;
    float v[8];
    #pragma unroll
    for (int j = 0; j < 8; ++j) v[j] = p[(size_t)j * ncols];
    union { unsigned u[4]; short8 s8; } r;
    r.u[0] = pk_bf16(v[0], v[1]);
    r.u[1] = pk_bf16(v[2], v[3]);
    r.u[2] = pk_bf16(v[4], v[5]);
    r.u[3] = pk_bf16(v[6], v[7]);
    return r.s8;
}

// ---------------- Stage 1: q/k/v MLP via MFMA, inline fp32 weight fragments ----------------
// grid (NROWS/MROWS, 3), block 256 = 4 waves. which: 0=q,1=k,2=v.
// V stored with each 32-key group permuted into PV B-frag slot order.
__global__ __launch_bounds__(256) void mlp_kernel(
    const float* __restrict__ x,
    const float* __restrict__ qW1, const float* __restrict__ qb1,
    const float* __restrict__ qW2, const float* __restrict__ qb2,
    const float* __restrict__ kW1, const float* __restrict__ kb1,
    const float* __restrict__ kW2, const float* __restrict__ kb2,
    const float* __restrict__ vW1, const float* __restrict__ vb1,
    const float* __restrict__ vW2, const float* __restrict__ vb2,
    __hip_bfloat16* __restrict__ Qb, __hip_bfloat16* __restrict__ Kb,
    __hip_bfloat16* __restrict__ Vt)
{
    const int blk   = blockIdx.x;
    const int which = blockIdx.y;
    const int t     = threadIdx.x;
    const int w     = t >> 6;
    const int lane  = t & 63;
    const int n     = lane & 31;
    const int hg    = lane >> 5;
    const int row0  = blk * MROWS;
    const int b     = row0 >> 11;          // batch
    const int s0    = row0 & (SS - 1);

    const float* W1 = (which == 0) ? qW1 : (which == 1) ? kW1 : vW1;
    const float* b1 = (which == 0) ? qb1 : (which == 1) ? kb1 : vb1;
    const float* W2 = (which == 0) ? qW2 : (which == 1) ? kW2 : vW2;
    const float* b2 = (which == 0) ? qb2 : (which == 1) ? kb2 : vb2;

    __shared__ __hip_bfloat16 smem[MROWS * HSTR];   // 16.9 KB, reused x -> h

    // ---- stage x as bf16, [row][k] stride XSTR ----
    {
        const int r  = t >> 3;              // 0..31
        const int k0 = (t & 7) * 8;         // 0..56
        const float* xp = x + (size_t)(row0 + r) * FF + k0;
        float4 a0 = *(const float4*)xp;
        float4 a1 = *(const float4*)(xp + 4);
        uint4 u = make_uint4(pk_bf16(a0.x, a0.y), pk_bf16(a0.z, a0.w),
                             pk_bf16(a1.x, a1.y), pk_bf16(a1.z, a1.w));
        *(uint4*)&smem[r * XSTR + k0] = u;
    }
    __syncthreads();

    // ---- layer1: two 32-channel tiles per wave ----
    const int c0a = w * 64, c0b = w * 64 + 32;
    float16v acc0, acc1;
    {
        #pragma unroll
        for (int g = 0; g < 4; ++g) {
            const float4 ba = *(const float4*)&b1[c0a + 8 * g + 4 * hg];
            const float4 bb = *(const float4*)&b1[c0b + 8 * g + 4 * hg];
            acc0[4*g+0] = ba.x; acc0[4*g+1] = ba.y; acc0[4*g+2] = ba.z; acc0[4*g+3] = ba.w;
            acc1[4*g+0] = bb.x; acc1[4*g+1] = bb.y; acc1[4*g+2] = bb.z; acc1[4*g+3] = bb.w;
        }
    }
    #pragma unroll
    for (int s = 0; s < 4; ++s) {
        const short8 xf = *(const short8*)&smem[n * XSTR + 16 * s + 8 * hg];  // B: x[row=n][k]
        const short8 a0 = wfrag_f32(W1, 16 * s + 8 * hg, c0a + n, HID);       // A: W1[k][c]
        const short8 a1 = wfrag_f32(W1, 16 * s + 8 * hg, c0b + n, HID);
        acc0 = __builtin_amdgcn_mfma_f32_32x32x16_bf16(a0, xf, acc0, 0, 0, 0);
        acc1 = __builtin_amdgcn_mfma_f32_32x32x16_bf16(a1, xf, acc1, 0, 0, 0);
    }
    // ---- ELU (native exp) ----
    #pragma unroll
    for (int i = 0; i < 16; ++i) {
        const float v0 = acc0[i], v1 = acc1[i];
        acc0[i] = (v0 > 0.f) ? v0 : (__expf(v0) - 1.f);
        acc1[i] = (v1 > 0.f) ? v1 : (__expf(v1) - 1.f);
    }
    __syncthreads();   // all x reads complete before overwrite

    // ---- write H^T pairs: sH[row=n][c], 8 dword writes per tile ----
    #pragma unroll
    for (int g = 0; g < 4; ++g) {
        const int ca = c0a + 8 * g + 4 * hg;
        const int cb = c0b + 8 * g + 4 * hg;
        *(unsigned*)&smem[n * HSTR + ca]     = pk_bf16(acc0[4*g+0], acc0[4*g+1]);
        *(unsigned*)&smem[n * HSTR + ca + 2] = pk_bf16(acc0[4*g+2], acc0[4*g+3]);
        *(unsigned*)&smem[n * HSTR + cb]     = pk_bf16(acc1[4*g+0], acc1[4*g+1]);
        *(unsigned*)&smem[n * HSTR + cb + 2] = pk_bf16(acc1[4*g+2], acc1[4*g+3]);
    }
    __syncthreads();

    // ---- layer2: one 32-channel tile per wave, K=256 ----
    const int d0 = w * 32;
    float16v acc;
    #pragma unroll
    for (int g = 0; g < 4; ++g) {
        const float4 bv = *(const float4*)&b2[d0 + 8 * g + 4 * hg];
        acc[4*g+0] = bv.x; acc[4*g+1] = bv.y; acc[4*g+2] = bv.z; acc[4*g+3] = bv.w;
    }
    #pragma unroll 8
    for (int s = 0; s < 16; ++s) {
        const short8 hf = *(const short8*)&smem[n * HSTR + 16 * s + 8 * hg];
        const short8 af = wfrag_f32(W2, 16 * s + 8 * hg, d0 + n, DD);         // A: W2[k][d]
        acc = __builtin_amdgcn_mfma_f32_32x32x16_bf16(af, hf, acc, 0, 0, 0);
    }

    // ---- epilogue: lane holds Y^T[d][row=n], d = d0 + 8g + 4hg + (r&3) ----
    if (which < 2) {
        const float sc = (which == 0) ? QSCALE : 1.0f;
        __hip_bfloat16* dst = (which == 0) ? Qb : Kb;
        #pragma unroll
        for (int g = 0; g < 4; ++g) {
            const int d  = d0 + 8 * g + 4 * hg;
            const int hh = d >> 4;
            const int dk = d & 15;
            const size_t base = ((size_t)(b * HH + hh) * SS + s0 + n) * DK + dk;
            uint2 u = make_uint2(pk_bf16(acc[4*g+0] * sc, acc[4*g+1] * sc),
                                 pk_bf16(acc[4*g+2] * sc, acc[4*g+3] * sc));
            *(uint2*)&dst[base] = u;
        }
    } else {
        // permuted column: 32-key group laid out in PV B-frag slot order
        const int pos = (n & 16) | (((n >> 2) & 1) << 3) | (((n >> 3) & 1) << 2) | (n & 3);
        #pragma unroll
        for (int r = 0; r < 16; ++r) {
            const int d  = d0 + 8 * (r >> 2) + 4 * hg + (r & 3);
            const int hh = d >> 4;
            const int dv = d & 15;
            Vt[((size_t)(b * HH + hh) * VROWS + dv) * SS + s0 + pos] = __float2bfloat16(acc[r]);
        }
        // ones-row (d=16) for l-via-MFMA (order irrelevant: all ones)
        const int hh2 = t >> 5, sl = t & 31;
        Vt[((size_t)(b * HH + hh2) * VROWS + 16) * SS + s0 + sl] = __float2bfloat16(1.0f);
    }
}

// ---------------- Stage 2: MFMA 32x32 flash attention, software-pipelined ----------------
// grid (NQB, HH, BB), block 512 = 8 waves: wave w -> q-tile (w>>2), key-split (w&3).
// Next-tile kf/B1/B2 prefetched before the exp chain (rotation); tail over-read lands in
// mapped ws. Native v_exp_f32; l via ones-row (C col 16); truncation bias cancels in O/l.
__global__ __launch_bounds__(512, 8) void attn_kernel(
    const __hip_bfloat16* __restrict__ Qb,
    const __hip_bfloat16* __restrict__ Kb,
    const __hip_bfloat16* __restrict__ Vt,
    float* __restrict__ partial)
{
    const int qblk = blockIdx.x;
    const int h    = blockIdx.y;
    const int b    = blockIdx.z;
    const int bh   = b * HH + h;
    const int t    = threadIdx.x;
    const int w    = t >> 6;
    const int lane = t & 63;
    const int qt   = w >> 2;
    const int sp   = w & 3;
    const int n    = lane & 31;
    const int hg   = lane >> 5;

    __shared__ float sO[8][32][DK];
    __shared__ float sL[8][32];
    __shared__ float sV[QPB][DK];
    __shared__ float sM2[8][DK];

    const size_t bh_s = (size_t)bh * SS;
    const int q0 = qblk * QPB + qt * 32;

    const short8 qf = *(const short8*)(Qb + (bh_s + q0 + n) * DK + hg * 8);

    // lane-fixed pointers
    const __hip_bfloat16* klp = Kb + (bh_s + sp * KRANGE + n) * DK + hg * 8;
    const int vd = (n < 16) ? n : 16;
    const __hip_bfloat16* vlp = Vt + ((size_t)bh * VROWS + vd) * SS + sp * KRANGE + 8 * hg;

    float16v acc;
    #pragma unroll
    for (int i = 0; i < 16; ++i) acc[i] = 0.f;
    float16v z;
    #pragma unroll
    for (int i = 0; i < 16; ++i) z[i] = 0.f;

    // prologue loads
    short8 kf = *(const short8*)klp;
    short8 B1 = *(const short8*)vlp;
    short8 B2 = *(const short8*)(vlp + 16);

    #pragma unroll 4
    for (int it = 0; it < KRANGE / 32; ++it) {
        // ---- prefetch next tile (over-reads on last iter land in mapped ws) ----
        klp += 32 * DK;
        vlp += 32;
        const short8 kf_n = *(const short8*)klp;
        const short8 B1_n = *(const short8*)vlp;
        const short8 B2_n = *(const short8*)(vlp + 16);

        // S^T[key][q]: col=n=q, key(reg,hg) = (reg&3)+8*(reg>>2)+4*hg
        const float16v st = __builtin_amdgcn_mfma_f32_32x32x16_bf16(kf, qf, z, 0, 0, 0);

        union { unsigned u[4]; short8 s8; } A1, A2;
        #pragma unroll
        for (int j = 0; j < 4; ++j)
            A1.u[j] = trunc_pk(fexp2(st[2 * j]),     fexp2(st[2 * j + 1]));
        #pragma unroll
        for (int j = 0; j < 4; ++j)
            A2.u[j] = trunc_pk(fexp2(st[2 * j + 8]), fexp2(st[2 * j + 9]));

        // O[q][d] (+ l in col 16): A-slots and B-slots share the permuted key order
        acc = __builtin_amdgcn_mfma_f32_32x32x16_bf16(A1.s8, B1, acc, 0, 0, 0);
        acc = __builtin_amdgcn_mfma_f32_32x32x16_bf16(A2.s8, B2, acc, 0, 0, 0);

        kf = kf_n; B1 = B1_n; B2 = B2_n;
    }

    // C-layout: col=n (0-15 -> O[q][d], 16 -> l[q]); q = (reg&3)+8*(reg>>2)+4*hg
    if (n < 16) {
        #pragma unroll
        for (int r = 0; r < 16; ++r) {
            const int q = (r & 3) + 8 * (r >> 2) + 4 * hg;
            sO[w][q][n] = acc[r];
        }
    } else if (n == 16) {
        #pragma unroll
        for (int r = 0; r < 16; ++r) {
            const int q = (r & 3) + 8 * (r >> 2) + 4 * hg;
            sL[w][q] = acc[r];
        }
    }
    __syncthreads();

    // merge 4 splits (pure sums) + normalize
    for (int it = t; it < QPB * DK; it += 512) {
        const int qt2 = it >> 9;
        const int q   = (it >> 4) & 31;
        const int d   = it & 15;
        const int w0  = qt2 * 4;
        const float Ov = sO[w0][q][d] + sO[w0+1][q][d] + sO[w0+2][q][d] + sO[w0+3][q][d];
        const float Lv = sL[w0][q] + sL[w0+1][q] + sL[w0+2][q] + sL[w0+3][q];
        sV[qt2 * 32 + q][d] = Ov / Lv;
    }
    __syncthreads();

    if (t < 128) {
        const int d = t & 15, g = t >> 4;
        float mx = sV[g * 8][d];
        #pragma unroll
        for (int i = 1; i < 8; ++i) mx = fmaxf(mx, sV[g * 8 + i][d]);
        sM2[g][d] = mx;
    }
    __syncthreads();

    if (t < DK) {
        float mx = sM2[0][t];
        #pragma unroll
        for (int g = 1; g < 8; ++g) mx = fmaxf(mx, sM2[g][t]);
        partial[((size_t)bh * NQB + qblk) * DK + t] = mx;
    }
}

// ---------------- Stage 3: reduce q-blocks -> output ----------------
__global__ void reduce_kernel(const float* __restrict__ partial,
                              float* __restrict__ out)
{
    const int g   = blockIdx.x * 256 + threadIdx.x;   // 0..511
    const int b   = g >> 7;
    const int col = g & 127;
    const int h   = col >> 4;
    const int d   = col & 15;
    float m = -1e30f;
    #pragma unroll
    for (int c = 0; c < NQB; ++c)
        m = fmaxf(m, partial[((size_t)(b * HH + h) * NQB + c) * DK + d]);
    out[g] = m;
}

extern "C" void kernel_launch(void* const* d_in, const int* in_sizes, int n_in,
                              void* d_out, int out_size, void* d_ws, size_t ws_size,
                              hipStream_t stream)
{
    const float* x   = (const float*)d_in[0];
    const float* qW1 = (const float*)d_in[1];
    const float* qb1 = (const float*)d_in[2];
    const float* qW2 = (const float*)d_in[3];
    const float* qb2 = (const float*)d_in[4];
    const float* kW1 = (const float*)d_in[5];
    const float* kb1 = (const float*)d_in[6];
    const float* kW2 = (const float*)d_in[7];
    const float* kb2 = (const float*)d_in[8];
    const float* vW1 = (const float*)d_in[9];
    const float* vb1 = (const float*)d_in[10];
    const float* vW2 = (const float*)d_in[11];
    const float* vb2 = (const float*)d_in[12];

    char* ws = (char*)d_ws;
    __hip_bfloat16* Qb  = (__hip_bfloat16*)(ws);                               // 2 MB
    __hip_bfloat16* Kb  = (__hip_bfloat16*)(ws + (size_t)2 * 1024 * 1024);     // 2 MB
    __hip_bfloat16* Vt  = (__hip_bfloat16*)(ws + (size_t)4 * 1024 * 1024);     // 2.23 MB (17 rows)
    float* partial      = (float*)(ws + (size_t)6784 * 1024);                  // 64 KB

    mlp_kernel<<<dim3(NROWS / MROWS, 3), 256, 0, stream>>>(
        x, qW1, qb1, qW2, qb2, kW1, kb1, kW2, kb2, vW1, vb1, vW2, vb2, Qb, Kb, Vt);

    attn_kernel<<<dim3(NQB, HH, BB), 512, 0, stream>>>(Qb, Kb, Vt, partial);

    reduce_kernel<<<2, 256, 0, stream>>>(partial, (float*)d_out);
}